// Round 19
// baseline (152.072 us; speedup 1.0000x reference)
//
#include <hip/hip_runtime.h>
#include <hip/hip_bf16.h>
#include <math.h>

namespace {
constexpr int NN  = 16384;
constexpr int NE  = 262144;
constexpr int DIM = 40;

constexpr float INV_SQRT3   = 0.5773502691896258f;
constexpr float A_PATH      = 0.2041241452319315f;      // 1/sqrt(24)
constexpr float INV_SQRT_NB = 0.31622776601683794f;     // 1/sqrt(10)
constexpr float H_SCALE     = 0.25f;                    // 1/sqrt(16)
constexpr float QSC_S       = 0.25f;
constexpr float QV_S        = 0.35355339059327373f;
constexpr float D00_S       = 1.0f / (16.0f * 1.4142135623730951f);
constexpr float D11_S       = 1.0f / (8.0f * 1.7320508075688772f * 1.4142135623730951f);

constexpr int BKP = 392;   // v_mfma B k-stride (fp16)
constexpr int K0P = 328;   // qq-GEMM path0 k-stride
constexpr int KCP = 264;   // qq-GEMM pathC k-stride
constexpr int BKTOT = 16 * K0P + 16 * KCP;   // 9472 shorts
constexpr int FEP = 40;    // feE padded row (fp16)
constexpr int FHP = 48;    // fhalf row stride (fp16)

constexpr int PREP_NODE_BLKS = NN / 256;                 // 64
constexpr int PREP_BV_BLKS   = 32 * BKP / 256;           // 49
constexpr int PREP_BK_BLKS   = BKTOT / 256;              // 37

constexpr int HIST_BLKS = NE / 256;                      // 1024
}

typedef __attribute__((ext_vector_type(8))) _Float16 f16x8;
typedef __attribute__((ext_vector_type(4))) _Float16 f16x4;
typedef __attribute__((ext_vector_type(4))) float f32x4;

static __device__ __forceinline__ void gload_lds16(const void* g, void* l) {
  __builtin_amdgcn_global_load_lds(
      (const __attribute__((address_space(1))) unsigned*)g,
      (__attribute__((address_space(3))) unsigned*)l, 16, 0, 0);
}

// ---------------------------------------------------------------------------
// prep_kernel (round-17 verified): node_qd + cnt zero + fhalf | Btv | Btk.
// Also zeroes the `done` ticket counter.
// ---------------------------------------------------------------------------
__global__ __launch_bounds__(256) void prep_kernel(
    const float* __restrict__ f,
    const float* __restrict__ Wq0, const float* __restrict__ Wq1,
    const float* __restrict__ Wd00, const float* __restrict__ Wd11,
    const float* __restrict__ w2v,   // fcv_w2
    const float* __restrict__ w2k,   // fck_w2
    float* __restrict__ qd,
    _Float16* __restrict__ fhalf,
    unsigned short* __restrict__ Btv,
    unsigned short* __restrict__ Btk,
    int* __restrict__ cnt,
    int* __restrict__ done)
{
  const int blk = blockIdx.x;
  if (blk == 0 && threadIdx.x == 0) *done = 0;
  if (blk < PREP_NODE_BLKS) {
    const int n = blk * 256 + threadIdx.x;
    cnt[n] = 0;

    float fs[16], fv[8][3];
    {
      const float4* fn4 = reinterpret_cast<const float4*>(f + (size_t)n * DIM);
#pragma unroll
      for (int i = 0; i < 10; i++) {
        float4 t = fn4[i];
        int base = i * 4;
#pragma unroll
        for (int k = 0; k < 4; k++) {
          float v = (k == 0) ? t.x : (k == 1) ? t.y : (k == 2) ? t.z : t.w;
          int idx = base + k;
          if (idx < 16) fs[idx] = v;
          else { int r = idx - 16; fv[r / 3][r % 3] = v; }
        }
      }
    }

    {
      _Float16 fh[FHP];
#pragma unroll
      for (int i = 0; i < 16; i++) fh[i] = (_Float16)fs[i];
#pragma unroll
      for (int i = 0; i < 8; i++)
#pragma unroll
        for (int c = 0; c < 3; c++) fh[16 + c * 8 + i] = (_Float16)fv[i][c];
#pragma unroll
      for (int i = 40; i < FHP; i++) fh[i] = (_Float16)0.f;
      f16x8* fp = reinterpret_cast<f16x8*>(fhalf + (size_t)n * FHP);
#pragma unroll
      for (int i = 0; i < FHP / 8; i++)
        fp[i] = *reinterpret_cast<const f16x8*>(&fh[i * 8]);
    }

    float out40[40];
    {
      float qsc[16];
#pragma unroll
      for (int o = 0; o < 16; o++) {
        float a = 0.f;
#pragma unroll
        for (int i = 0; i < 16; i++) a += fs[i] * Wq0[i * 16 + o];
        qsc[o] = a * QSC_S;
      }
#pragma unroll
      for (int j = 0; j < 16; j++) {
        float a = 0.f;
#pragma unroll
        for (int i = 0; i < 16; i++) a += qsc[i] * Wd00[i * 16 + j];
        out40[j] = a * D00_S;
      }
    }
    {
      float qv[8][3];
#pragma unroll
      for (int o = 0; o < 8; o++)
#pragma unroll
        for (int c = 0; c < 3; c++) {
          float a = 0.f;
#pragma unroll
          for (int i = 0; i < 8; i++) a += fv[i][c] * Wq1[i * 8 + o];
          qv[o][c] = a * QV_S;
        }
#pragma unroll
      for (int j = 0; j < 8; j++)
#pragma unroll
        for (int c = 0; c < 3; c++) {
          float a = 0.f;
#pragma unroll
          for (int i = 0; i < 8; i++) a += qv[i][c] * Wd11[i * 8 + j];
          out40[16 + j * 3 + c] = a * D11_S;
        }
    }

    float4* op = reinterpret_cast<float4*>(qd + (size_t)n * DIM);
#pragma unroll
    for (int i = 0; i < 10; i++)
      op[i] = make_float4(out40[4 * i], out40[4 * i + 1], out40[4 * i + 2], out40[4 * i + 3]);

  } else if (blk < PREP_NODE_BLKS + PREP_BV_BLKS) {
    int t = (blk - PREP_NODE_BLKS) * 256 + threadIdx.x;
    int col = t / BKP, kp = t % BKP;
    float val = 0.f;
    if (kp < 384 && col < 24) {
      if (kp < 256) {
        int r = kp >> 4, i = kp & 15;
        if (col < 16) val = A_PATH * w2v[r * 576 + i * 16 + col];
        else          val = A_PATH * w2v[r * 576 + 384 + i * 8 + (col - 16)];
      } else {
        int k2 = kp - 256; int r = k2 >> 3, i = k2 & 7;
        if (col < 16) val = A_PATH * INV_SQRT3 * w2v[r * 576 + 256 + i * 16 + col];
        else          val = A_PATH * w2v[r * 576 + 512 + i * 8 + (col - 16)];
      }
    }
    _Float16 hv = (_Float16)val;
    Btv[t] = __builtin_bit_cast(unsigned short, hv);

  } else {
    int t = (blk - PREP_NODE_BLKS - PREP_BV_BLKS) * 256 + threadIdx.x;
    float val = 0.f;
    if (t < 16 * K0P) {
      int r = t / K0P, k = t % K0P;
      if (k < 256)      { int i = k >> 4, o = k & 15; val = w2k[r * 576 + i * 16 + o]; }
      else if (k < 320) { int kk = k - 256; int i = kk >> 3, o = kk & 7;
                          val = w2k[r * 576 + 512 + i * 8 + o]; }
    } else {
      int t2 = t - 16 * K0P;
      int r = t2 / KCP, k = t2 % KCP;
      if (k < 128)      { int i = k >> 4, o = k & 15;
                          val = INV_SQRT3 * w2k[r * 576 + 256 + i * 16 + o]; }
      else if (k < 256) { int kk = k - 128; int i = kk >> 3, o = kk & 7;
                          val = w2k[r * 576 + 384 + i * 8 + o]; }
    }
    _Float16 hv = (_Float16)val;
    Btk[t] = __builtin_bit_cast(unsigned short, hv);
  }
}

// ---------------------------------------------------------------------------
// qq_hist_kernel: blocks [0,1024) = hist (zero out + cnt atomic) with
// LAST-BLOCK-DONE scan fused in (ticket + threadfence); blocks
// [1024,1280) = qq via MFMA (round-11 verified math, fp16 output).
// ---------------------------------------------------------------------------
__global__ __launch_bounds__(256) void qq_hist_kernel(
    const int*   __restrict__ ei,
    int*         __restrict__ cnt,
    float*       __restrict__ out,
    const float* __restrict__ f,
    const float* __restrict__ qd,
    const unsigned short* __restrict__ Btk,
    _Float16*    __restrict__ qq16,
    int*   __restrict__ done,
    int*   __restrict__ off,
    float* __restrict__ z)
{
  __shared__ __attribute__((aligned(16))) unsigned short BL[BKTOT];
  __shared__ float fsT[16][65];
  __shared__ float fvT[24][65];
  __shared__ float qd0T[16][65];
  __shared__ float qdvT[24][65];
  __shared__ int partS[256];
  __shared__ int lastFlag;

  const int tid = threadIdx.x;

  if (blockIdx.x < HIST_BLKS) {
    const int e = blockIdx.x * 256 + tid;
#pragma unroll
    for (int i = 0; i < 3; i++) {
      int idx = e + i * NE;
      if (idx < NN * DIM) out[idx] = 0.f;
    }
    atomicAdd(&cnt[ei[NE + e]], 1);
    __threadfence();
    __syncthreads();
    if (tid == 0) {
      int t = atomicAdd(done, 1);
      lastFlag = (t == HIST_BLKS - 1) ? 1 : 0;
    }
    __syncthreads();
    if (!lastFlag) return;
    __threadfence();   // acquire: all hist blocks' cnt atomics visible

    // ---- fused scan: 64 nodes per thread ----
    const int nb = tid * 64;
    int s = 0;
    for (int k = 0; k < 64; k++) s += cnt[nb + k];
    partS[tid] = s;
    __syncthreads();
    for (int d = 1; d < 256; d <<= 1) {
      int v = (tid >= d) ? partS[tid - d] : 0;
      __syncthreads();
      partS[tid] += v;
      __syncthreads();
    }
    int run = (tid == 0) ? 0 : partS[tid - 1];
    for (int k = 0; k < 64; k++) {
      int c = cnt[nb + k];
      off[nb + k] = run;
      run += c;
      z[nb + k] = 0.f;
    }
    return;
  }

  const int base = (blockIdx.x - HIST_BLKS) * 64;

  {
    const char* src = (const char*)Btk;
    char* dst = (char*)BL;
#pragma unroll
    for (int k2 = 0; k2 < 4; k2++) {
      int o = (k2 * 256 + tid) * 16;
      gload_lds16(src + o, dst + o);
    }
    if (tid < 160) {
      int o = (1024 + tid) * 16;
      gload_lds16(src + o, dst + o);
    }
  }

  const int m = tid & 63;
  const int q = tid >> 6;
  const int n = base + m;

  if (q == 0) {
    const float4* f4 = reinterpret_cast<const float4*>(f + (size_t)n * DIM);
    float v[40];
#pragma unroll
    for (int i = 0; i < 10; i++) {
      float4 t = f4[i];
      v[4 * i] = t.x; v[4 * i + 1] = t.y; v[4 * i + 2] = t.z; v[4 * i + 3] = t.w;
    }
#pragma unroll
    for (int i = 0; i < 16; i++) fsT[i][m] = v[i];
#pragma unroll
    for (int k = 0; k < 24; k++) fvT[(k % 3) * 8 + (k / 3)][m] = v[16 + k];
  } else if (q == 1) {
    const float4* q4 = reinterpret_cast<const float4*>(qd + (size_t)n * DIM);
    float v[40];
#pragma unroll
    for (int i = 0; i < 10; i++) {
      float4 t = q4[i];
      v[4 * i] = t.x; v[4 * i + 1] = t.y; v[4 * i + 2] = t.z; v[4 * i + 3] = t.w;
    }
#pragma unroll
    for (int i = 0; i < 16; i++) qd0T[i][m] = v[i];
#pragma unroll
    for (int k = 0; k < 24; k++) qdvT[(k % 3) * 8 + (k / 3)][m] = v[16 + k];
  }
  __syncthreads();

  const int w    = tid >> 6;
  const int l    = tid & 63;
  const int row  = l & 15;
  const int kb   = l >> 4;
  const int mrow = w * 16 + row;
  const int col  = l & 15;

  f32x4 p0  = {0.f, 0.f, 0.f, 0.f};
  f32x4 pcA = {0.f, 0.f, 0.f, 0.f}, pcB = {0.f, 0.f, 0.f, 0.f}, pcC = {0.f, 0.f, 0.f, 0.f};

#pragma unroll
  for (int s = 0; s < 10; s++) {
    f16x8 a;
    if (s < 8) {
      const int i  = 2 * s + (kb >> 1);
      const int o0 = (kb & 1) * 8;
      const float fsv = fsT[i][mrow];
#pragma unroll
      for (int j = 0; j < 8; j++) a[j] = (_Float16)(fsv * qd0T[o0 + j][mrow]);
    } else {
      const int i = (s - 8) * 4 + kb;
      const float fv0 = fvT[i][mrow], fv1 = fvT[8 + i][mrow], fv2 = fvT[16 + i][mrow];
#pragma unroll
      for (int j = 0; j < 8; j++)
        a[j] = (_Float16)(fv0 * qdvT[j][mrow] + fv1 * qdvT[8 + j][mrow]
                          + fv2 * qdvT[16 + j][mrow]);
    }
    const int k0 = s * 32 + kb * 8;
    f16x8 b = *reinterpret_cast<const f16x8*>(&BL[col * K0P + k0]);
    p0 = __builtin_amdgcn_mfma_f32_16x16x32_f16(a, b, p0, 0, 0, 0);
  }

#pragma unroll
  for (int c = 0; c < 3; c++) {
    f32x4* pc = (c == 0) ? &pcA : (c == 1) ? &pcB : &pcC;
#pragma unroll
    for (int s = 0; s < 8; s++) {
      f16x8 a;
      if (s < 4) {
        const int i  = 2 * s + (kb >> 1);
        const int o0 = (kb & 1) * 8;
        const float fvv = fvT[c * 8 + i][mrow];
#pragma unroll
        for (int j = 0; j < 8; j++) a[j] = (_Float16)(fvv * qd0T[o0 + j][mrow]);
      } else {
        const int i = (s - 4) * 4 + kb;
        const float fsv = fsT[i][mrow];
#pragma unroll
        for (int j = 0; j < 8; j++) a[j] = (_Float16)(fsv * qdvT[c * 8 + j][mrow]);
      }
      const int k0 = s * 32 + kb * 8;
      f16x8 b = *reinterpret_cast<const f16x8*>(&BL[16 * K0P + col * KCP + k0]);
      *pc = __builtin_amdgcn_mfma_f32_16x16x32_f16(a, b, *pc, 0, 0, 0);
    }
  }

#pragma unroll
  for (int j = 0; j < 4; j++) {
    const int me = w * 16 + kb * 4 + j;
    f16x4 o;
    o[0] = (_Float16)(A_PATH * p0[j]);
    o[1] = (_Float16)(A_PATH * pcA[j]);
    o[2] = (_Float16)(A_PATH * pcB[j]);
    o[3] = (_Float16)(A_PATH * pcC[j]);
    *reinterpret_cast<f16x4*>(qq16 + ((size_t)(base + me) * 16 + col) * 4) = o;
  }
}

// ---------------------------------------------------------------------------
// edge_kernel (round-17 verified)
// ---------------------------------------------------------------------------
__global__ __launch_bounds__(256) void edge_kernel(
    const int*   __restrict__ ei,
    const float* __restrict__ elen,
    const float* __restrict__ esh,
    const float* __restrict__ emb,
    const float* __restrict__ w1k,    // fck_w1
    const float* __restrict__ w1v,    // fcv_w1
    const _Float16* __restrict__ qq16,
    int*   __restrict__ off,
    float4* __restrict__ edata,       // [NE][4] float4 (64B per edge, by rank)
    float* __restrict__ z)
{
  const int gid = blockIdx.x * 256 + threadIdx.x;

  const int src = ei[gid];
  const int dst = ei[NE + gid];
  const int rk = atomicAdd(&off[dst], 1);

  float el[10];
  const float2* e2 = reinterpret_cast<const float2*>(emb + (size_t)gid * 10);
#pragma unroll
  for (int b = 0; b < 5; b++) { float2 t = e2[b]; el[2 * b] = t.x; el[2 * b + 1] = t.y; }

  float h[16];
#pragma unroll
  for (int j = 0; j < 16; j++) {
    float a = 0.f;
#pragma unroll
    for (int b = 0; b < 10; b++) a += el[b] * w1k[b * 16 + j];
    a *= INV_SQRT_NB;
    float sig = 1.0f / (1.0f + __expf(-a));
    h[j] = a * sig * H_SCALE;
  }

  float4 sh4 = reinterpret_cast<const float4*>(esh)[gid];
  const f16x8* q8 = reinterpret_cast<const f16x8*>(qq16 + (size_t)dst * 64);
  float s = 0.f;
#pragma unroll
  for (int i = 0; i < 8; i++) {
    f16x8 qv = q8[i];
    s += h[2 * i] * (sh4.x * (float)qv[0] + sh4.y * (float)qv[1]
                   + sh4.z * (float)qv[2] + sh4.w * (float)qv[3]);
    s += h[2 * i + 1] * (sh4.x * (float)qv[4] + sh4.y * (float)qv[5]
                       + sh4.z * (float)qv[6] + sh4.w * (float)qv[7]);
  }

  float len = elen[gid];
  float x = 10.0f * (1.0f - len * (1.0f / 1.3f));
  float cut = (x > 0.f) ? __expf(-1.0f / x) : 0.f;
  float ev = cut * __expf(s);
  atomicAdd(&z[dst], ev);

  f16x8 hv0, hv1;
#pragma unroll
  for (int j = 0; j < 16; j++) {
    float a = 0.f;
#pragma unroll
    for (int b = 0; b < 10; b++) a += el[b] * w1v[b * 16 + j];
    a *= INV_SQRT_NB;
    float sig = 1.0f / (1.0f + __expf(-a));
    _Float16 hh = (_Float16)(a * sig * H_SCALE);
    if (j < 8) hv0[j] = hh; else hv1[j - 8] = hh;
  }

  float4* ep = edata + (size_t)rk * 4;
  ep[0] = __builtin_bit_cast(float4, hv0);
  ep[1] = __builtin_bit_cast(float4, hv1);
  ep[2] = sh4;
  ep[3] = make_float4(__int_as_float(src), __int_as_float(dst), ev, 0.f);
}

// ---------------------------------------------------------------------------
// V-pass via fp16 MFMA (round-17 verified, unchanged)
// ---------------------------------------------------------------------------
__global__ __launch_bounds__(512) void v_mfma_kernel(
    const _Float16* __restrict__ fhalf,
    const float4* __restrict__ edata,
    const float* __restrict__ z,
    const unsigned short* __restrict__ Bt,
    float* __restrict__ fout)
{
  __shared__ __attribute__((aligned(16))) unsigned short BtL[32][BKP];
  __shared__ __attribute__((aligned(16))) _Float16 h_s[2][64][18];
  __shared__ __attribute__((aligned(16))) _Float16 feE[2][64][FEP];
  __shared__ float scal[2][64][5];
  __shared__ int   nid[2][64];
  __shared__ float rows[2][64][41];
  __shared__ int seg_start[2][64], seg_len[2][64], seg_nid[2][64];
  __shared__ int nseg_s[2];

  const int tid = threadIdx.x;

  {
    const char* src = (const char*)Bt;
    char* dst = (char*)&BtL[0][0];
#pragma unroll
    for (int k = 0; k < 3; k++) {
      int off = (k * 512 + tid) * 16;
      gload_lds16(src + off, dst + off);
    }
    if (tid < 32) {
      int off = (1536 + tid) * 16;
      gload_lds16(src + off, dst + off);
    }
  }

  const int hf  = tid >> 8;
  const int t2  = tid & 255;
  const int m   = t2 & 63;
  const int q   = t2 >> 6;
  const int base = blockIdx.x * 128 + hf * 64;
  const float4* ed = edata + (size_t)(base + m) * 4;

  if (q == 0) {
    float4 v3 = ed[3];
    float4 sh4 = ed[2];
    int dn = __float_as_int(v3.y);
    float zz = z[dn]; zz = (zz == 0.f) ? 1.f : zz;
    float ev = v3.z;
    float wgt = sqrtf(fmaxf(ev / zz, 0.f));
    scal[hf][m][0] = sh4.x; scal[hf][m][1] = sh4.y;
    scal[hf][m][2] = sh4.z; scal[hf][m][3] = sh4.w;
    scal[hf][m][4] = wgt;
    nid[hf][m] = dn;
  } else if (q == 3) {
    int sn = __float_as_int(ed[3].x);
    const f16x8* fp8 = reinterpret_cast<const f16x8*>(fhalf + (size_t)sn * FHP);
    f16x8* fe = reinterpret_cast<f16x8*>(&feE[hf][m][0]);
#pragma unroll
    for (int i = 0; i < 5; i++) fe[i] = fp8[i];
  } else if (q == 1) {
    f16x8 h0 = __builtin_bit_cast(f16x8, ed[0]);
    f16x8 h1 = __builtin_bit_cast(f16x8, ed[1]);
#pragma unroll
    for (int j = 0; j < 8; j++) {
      h_s[hf][m][j]     = h0[j];
      h_s[hf][m][8 + j] = h1[j];
    }
  }
  __syncthreads();

  const int w    = t2 >> 6;
  const int l    = t2 & 63;
  const int row  = l & 15;
  const int kb   = l >> 4;
  const int mrow = w * 16 + row;
  const int col  = l & 15;

  const int i0 = (kb & 1) * 8;
  f16x8 afs = *reinterpret_cast<const f16x8*>(&feE[hf][mrow][i0]);
  f16x8 afv0 = *reinterpret_cast<const f16x8*>(&feE[hf][mrow][16]);
  f16x8 afv1 = *reinterpret_cast<const f16x8*>(&feE[hf][mrow][24]);
  f16x8 afv2 = *reinterpret_cast<const f16x8*>(&feE[hf][mrow][32]);

  f32x4 pfs0 = {0.f, 0.f, 0.f, 0.f}, pfs1 = {0.f, 0.f, 0.f, 0.f};
  f32x4 pc0_0 = {0.f, 0.f, 0.f, 0.f}, pc0_1 = {0.f, 0.f, 0.f, 0.f}, pc0_2 = {0.f, 0.f, 0.f, 0.f};
  f32x4 pc1_0 = {0.f, 0.f, 0.f, 0.f}, pc1_1 = {0.f, 0.f, 0.f, 0.f}, pc1_2 = {0.f, 0.f, 0.f, 0.f};

#pragma unroll
  for (int s = 0; s < 8; s++) {
    const int r  = 2 * s + (kb >> 1);
    const _Float16 hr = h_s[hf][mrow][r];
    f16x8 a;
#pragma unroll
    for (int j = 0; j < 8; j++) a[j] = hr * afs[j];
    const int k0 = s * 32 + kb * 8;
    f16x8 b0 = *reinterpret_cast<const f16x8*>(&BtL[col][k0]);
    f16x8 b1 = *reinterpret_cast<const f16x8*>(&BtL[16 + col][k0]);
    pfs0 = __builtin_amdgcn_mfma_f32_16x16x32_f16(a, b0, pfs0, 0, 0, 0);
    pfs1 = __builtin_amdgcn_mfma_f32_16x16x32_f16(a, b1, pfs1, 0, 0, 0);
  }

#pragma unroll
  for (int s = 0; s < 4; s++) {
    const int r = 4 * s + kb;
    const _Float16 hr = h_s[hf][mrow][r];
    const int k0 = 256 + s * 32 + kb * 8;
    f16x8 b0 = *reinterpret_cast<const f16x8*>(&BtL[col][k0]);
    f16x8 b1 = *reinterpret_cast<const f16x8*>(&BtL[16 + col][k0]);
#pragma unroll
    for (int c = 0; c < 3; c++) {
      const f16x8 av = (c == 0) ? afv0 : (c == 1) ? afv1 : afv2;
      f16x8 a;
#pragma unroll
      for (int j = 0; j < 8; j++) a[j] = hr * av[j];
      f32x4* p0 = (c == 0) ? &pc0_0 : (c == 1) ? &pc0_1 : &pc0_2;
      f32x4* p1 = (c == 0) ? &pc1_0 : (c == 1) ? &pc1_1 : &pc1_2;
      *p0 = __builtin_amdgcn_mfma_f32_16x16x32_f16(a, b0, *p0, 0, 0, 0);
      *p1 = __builtin_amdgcn_mfma_f32_16x16x32_f16(a, b1, *p1, 0, 0, 0);
    }
  }

#pragma unroll
  for (int j = 0; j < 4; j++) {
    const int me = w * 16 + kb * 4 + j;
    const float sh0 = scal[hf][me][0], sh1 = scal[hf][me][1];
    const float sh2 = scal[hf][me][2], sh3 = scal[hf][me][3];
    const float wg = scal[hf][me][4];
    float vsc = sh0 * pfs0[j] + sh1 * pc0_0[j] + sh2 * pc0_1[j] + sh3 * pc0_2[j];
    rows[hf][me][col] = wg * vsc;
    if (col < 8) {
      rows[hf][me][16 + col * 3 + 0] = wg * (sh1 * pfs1[j] + sh0 * pc1_0[j]);
      rows[hf][me][16 + col * 3 + 1] = wg * (sh2 * pfs1[j] + sh0 * pc1_1[j]);
      rows[hf][me][16 + col * 3 + 2] = wg * (sh3 * pfs1[j] + sh0 * pc1_2[j]);
    }
  }
  __syncthreads();

  if (t2 < 64) {
    bool head = (m == 0) || (nid[hf][m] != nid[hf][m - 1]);
    unsigned long long mask = __ballot(head);
    if (t2 == 0) nseg_s[hf] = __popcll(mask);
    if (head) {
      int idx = __popcll(mask & ((1ull << m) - 1ull));
      unsigned long long higher = (m == 63) ? 0ull : (mask >> (m + 1));
      int len = higher ? __ffsll((long long)higher) : (64 - m);
      seg_start[hf][idx] = m; seg_len[hf][idx] = len; seg_nid[hf][idx] = nid[hf][m];
    }
  }
  __syncthreads();

  const int nseg = nseg_s[hf];
  const int d = t2 & 63;
  const int g = t2 >> 6;
  if (d < DIM) {
    for (int s = g; s < nseg; s += 4) {
      const int st = seg_start[hf][s], ln = seg_len[hf][s];
      float acc = 0.f;
      for (int k2 = 0; k2 < ln; k2++) acc += rows[hf][st + k2][d];
      float* fo = &fout[(size_t)seg_nid[hf][s] * DIM + d];
      if (s > 0 && s < nseg - 1) *fo = acc;
      else atomicAdd(fo, acc);
    }
  }
}

extern "C" void kernel_launch(void* const* d_in, const int* in_sizes, int n_in,
                              void* d_out, int out_size, void* d_ws, size_t ws_size,
                              hipStream_t stream) {
  const float* f      = (const float*)d_in[0];
  const int*   ei     = (const int*)d_in[1];
  const float* elen   = (const float*)d_in[2];
  const float* esh    = (const float*)d_in[3];
  const float* emb    = (const float*)d_in[4];
  const float* Wq0    = (const float*)d_in[5];
  const float* Wq1    = (const float*)d_in[6];
  const float* fck_w1 = (const float*)d_in[7];
  const float* fck_w2 = (const float*)d_in[8];
  const float* fcv_w1 = (const float*)d_in[9];
  const float* fcv_w2 = (const float*)d_in[10];
  const float* Wd00   = (const float*)d_in[11];
  const float* Wd11   = (const float*)d_in[12];

  float* out = (float*)d_out;

  char* ws = (char*)d_ws;
  float* qd       = (float*)ws;  ws += (size_t)NN * DIM * 4;
  float* z        = (float*)ws;  ws += (size_t)NN * 4;
  int*   cnt      = (int*)ws;    ws += (size_t)NN * 4;
  int*   off      = (int*)ws;    ws += (size_t)NN * 4;
  int*   done     = (int*)ws;    ws += 256;
  ws = (char*)(((size_t)ws + 63) & ~(size_t)63);
  float4* edata   = (float4*)ws; ws += (size_t)NE * 64;
  _Float16* qq16  = (_Float16*)ws; ws += (size_t)NN * 64 * 2;
  _Float16* fhalf = (_Float16*)ws; ws += (size_t)NN * FHP * 2;
  unsigned short* Btv = (unsigned short*)ws;  ws += (size_t)32 * BKP * 2;
  unsigned short* Btk = (unsigned short*)ws;  ws += (size_t)BKTOT * 2;

  prep_kernel<<<PREP_NODE_BLKS + PREP_BV_BLKS + PREP_BK_BLKS, 256, 0, stream>>>(
      f, Wq0, Wq1, Wd00, Wd11, fcv_w2, fck_w2, qd, fhalf, Btv, Btk, cnt, done);
  qq_hist_kernel<<<HIST_BLKS + NN / 64, 256, 0, stream>>>(
      ei, cnt, out, f, qd, Btk, qq16, done, off, z);
  edge_kernel<<<NE / 256, 256, 0, stream>>>(ei, elen, esh, emb, fck_w1, fcv_w1,
                                            qq16, off, edata, z);
  v_mfma_kernel<<<NE / 128, 512, 0, stream>>>(fhalf, edata, z, Btv, out);
}

// Round 20
// 101.062 us; speedup vs baseline: 1.5047x; 1.5047x over previous
//
#include <hip/hip_runtime.h>
#include <hip/hip_bf16.h>
#include <math.h>

namespace {
constexpr int NN  = 16384;
constexpr int NE  = 262144;
constexpr int DIM = 40;

constexpr float INV_SQRT3   = 0.5773502691896258f;
constexpr float A_PATH      = 0.2041241452319315f;      // 1/sqrt(24)
constexpr float INV_SQRT_NB = 0.31622776601683794f;     // 1/sqrt(10)
constexpr float H_SCALE     = 0.25f;                    // 1/sqrt(16)
constexpr float QSC_S       = 0.25f;
constexpr float QV_S        = 0.35355339059327373f;
constexpr float D00_S       = 1.0f / (16.0f * 1.4142135623730951f);
constexpr float D11_S       = 1.0f / (8.0f * 1.7320508075688772f * 1.4142135623730951f);

constexpr int BKP = 392;   // v_mfma B k-stride (fp16)
constexpr int K0P = 328;   // qq-GEMM path0 k-stride
constexpr int KCP = 264;   // qq-GEMM pathC k-stride
constexpr int BKTOT = 16 * K0P + 16 * KCP;   // 9472 shorts
constexpr int FEP = 40;    // feE padded row (fp16)
constexpr int FHP = 48;    // fhalf row stride (fp16): 96B, 16B-aligned

constexpr int PREP_NODE_BLKS = NN / 256;                 // 64
constexpr int PREP_BV_BLKS   = 32 * BKP / 256;           // 49
constexpr int PREP_BK_BLKS   = BKTOT / 256;              // 37

constexpr int HIST_BLKS = NE / 256;                      // 1024
}

typedef __attribute__((ext_vector_type(8))) _Float16 f16x8;
typedef __attribute__((ext_vector_type(4))) _Float16 f16x4;
typedef __attribute__((ext_vector_type(4))) float f32x4;

static __device__ __forceinline__ void gload_lds16(const void* g, void* l) {
  __builtin_amdgcn_global_load_lds(
      (const __attribute__((address_space(1))) unsigned*)g,
      (__attribute__((address_space(3))) unsigned*)l, 16, 0, 0);
}

// ---------------------------------------------------------------------------
// prep_kernel: node_qd + cnt zero + fhalf (fp16 feE-layout row) | Btv | Btk
// ---------------------------------------------------------------------------
__global__ __launch_bounds__(256) void prep_kernel(
    const float* __restrict__ f,
    const float* __restrict__ Wq0, const float* __restrict__ Wq1,
    const float* __restrict__ Wd00, const float* __restrict__ Wd11,
    const float* __restrict__ w2v,   // fcv_w2
    const float* __restrict__ w2k,   // fck_w2
    float* __restrict__ qd,
    _Float16* __restrict__ fhalf,
    unsigned short* __restrict__ Btv,
    unsigned short* __restrict__ Btk,
    int* __restrict__ cnt)
{
  const int blk = blockIdx.x;
  if (blk < PREP_NODE_BLKS) {
    const int n = blk * 256 + threadIdx.x;
    cnt[n] = 0;

    float fs[16], fv[8][3];
    {
      const float4* fn4 = reinterpret_cast<const float4*>(f + (size_t)n * DIM);
#pragma unroll
      for (int i = 0; i < 10; i++) {
        float4 t = fn4[i];
        int base = i * 4;
#pragma unroll
        for (int k = 0; k < 4; k++) {
          float v = (k == 0) ? t.x : (k == 1) ? t.y : (k == 2) ? t.z : t.w;
          int idx = base + k;
          if (idx < 16) fs[idx] = v;
          else { int r = idx - 16; fv[r / 3][r % 3] = v; }
        }
      }
    }

    // fhalf row in feE layout: [0..15]=fs, [16+c*8+i]=fv[i][c]
    {
      _Float16 fh[FHP];
#pragma unroll
      for (int i = 0; i < 16; i++) fh[i] = (_Float16)fs[i];
#pragma unroll
      for (int i = 0; i < 8; i++)
#pragma unroll
        for (int c = 0; c < 3; c++) fh[16 + c * 8 + i] = (_Float16)fv[i][c];
#pragma unroll
      for (int i = 40; i < FHP; i++) fh[i] = (_Float16)0.f;
      f16x8* fp = reinterpret_cast<f16x8*>(fhalf + (size_t)n * FHP);
#pragma unroll
      for (int i = 0; i < FHP / 8; i++)
        fp[i] = *reinterpret_cast<const f16x8*>(&fh[i * 8]);
    }

    float out[40];
    {
      float qsc[16];
#pragma unroll
      for (int o = 0; o < 16; o++) {
        float a = 0.f;
#pragma unroll
        for (int i = 0; i < 16; i++) a += fs[i] * Wq0[i * 16 + o];
        qsc[o] = a * QSC_S;
      }
#pragma unroll
      for (int j = 0; j < 16; j++) {
        float a = 0.f;
#pragma unroll
        for (int i = 0; i < 16; i++) a += qsc[i] * Wd00[i * 16 + j];
        out[j] = a * D00_S;
      }
    }
    {
      float qv[8][3];
#pragma unroll
      for (int o = 0; o < 8; o++)
#pragma unroll
        for (int c = 0; c < 3; c++) {
          float a = 0.f;
#pragma unroll
          for (int i = 0; i < 8; i++) a += fv[i][c] * Wq1[i * 8 + o];
          qv[o][c] = a * QV_S;
        }
#pragma unroll
      for (int j = 0; j < 8; j++)
#pragma unroll
        for (int c = 0; c < 3; c++) {
          float a = 0.f;
#pragma unroll
          for (int i = 0; i < 8; i++) a += qv[i][c] * Wd11[i * 8 + j];
          out[16 + j * 3 + c] = a * D11_S;
        }
    }

    float4* op = reinterpret_cast<float4*>(qd + (size_t)n * DIM);
#pragma unroll
    for (int i = 0; i < 10; i++)
      op[i] = make_float4(out[4 * i], out[4 * i + 1], out[4 * i + 2], out[4 * i + 3]);

  } else if (blk < PREP_NODE_BLKS + PREP_BV_BLKS) {
    int t = (blk - PREP_NODE_BLKS) * 256 + threadIdx.x;
    int col = t / BKP, kp = t % BKP;
    float val = 0.f;
    if (kp < 384 && col < 24) {
      if (kp < 256) {
        int r = kp >> 4, i = kp & 15;
        if (col < 16) val = A_PATH * w2v[r * 576 + i * 16 + col];
        else          val = A_PATH * w2v[r * 576 + 384 + i * 8 + (col - 16)];
      } else {
        int k2 = kp - 256; int r = k2 >> 3, i = k2 & 7;
        if (col < 16) val = A_PATH * INV_SQRT3 * w2v[r * 576 + 256 + i * 16 + col];
        else          val = A_PATH * w2v[r * 576 + 512 + i * 8 + (col - 16)];
      }
    }
    _Float16 hv = (_Float16)val;
    Btv[t] = __builtin_bit_cast(unsigned short, hv);

  } else {
    int t = (blk - PREP_NODE_BLKS - PREP_BV_BLKS) * 256 + threadIdx.x;
    float val = 0.f;
    if (t < 16 * K0P) {
      int r = t / K0P, k = t % K0P;
      if (k < 256)      { int i = k >> 4, o = k & 15; val = w2k[r * 576 + i * 16 + o]; }
      else if (k < 320) { int kk = k - 256; int i = kk >> 3, o = kk & 7;
                          val = w2k[r * 576 + 512 + i * 8 + o]; }
    } else {
      int t2 = t - 16 * K0P;
      int r = t2 / KCP, k = t2 % KCP;
      if (k < 128)      { int i = k >> 4, o = k & 15;
                          val = INV_SQRT3 * w2k[r * 576 + 256 + i * 16 + o]; }
      else if (k < 256) { int kk = k - 128; int i = kk >> 3, o = kk & 7;
                          val = w2k[r * 576 + 384 + i * 8 + o]; }
    }
    _Float16 hv = (_Float16)val;
    Btk[t] = __builtin_bit_cast(unsigned short, hv);
  }
}

// ---------------------------------------------------------------------------
// qq_hist_kernel: blocks [0,1024) = hist (zero out + cnt atomic);
// blocks [1024, 1024+256) = qq via MFMA (round-11 verified math, fp16 output).
// Both depend only on prep; fusing overlaps hist under qq.
// ---------------------------------------------------------------------------
__global__ __launch_bounds__(256) void qq_hist_kernel(
    const int*   __restrict__ ei,
    int*         __restrict__ cnt,
    float*       __restrict__ out,
    const float* __restrict__ f,
    const float* __restrict__ qd,
    const unsigned short* __restrict__ Btk,
    _Float16*    __restrict__ qq16)
{
  __shared__ __attribute__((aligned(16))) unsigned short BL[BKTOT];
  __shared__ float fsT[16][65];
  __shared__ float fvT[24][65];
  __shared__ float qd0T[16][65];
  __shared__ float qdvT[24][65];

  if (blockIdx.x < HIST_BLKS) {
    const int e = blockIdx.x * 256 + threadIdx.x;
#pragma unroll
    for (int i = 0; i < 3; i++) {
      int idx = e + i * NE;
      if (idx < NN * DIM) out[idx] = 0.f;
    }
    atomicAdd(&cnt[ei[NE + e]], 1);
    return;
  }

  const int tid  = threadIdx.x;
  const int base = (blockIdx.x - HIST_BLKS) * 64;

  {
    const char* src = (const char*)Btk;
    char* dst = (char*)BL;
#pragma unroll
    for (int k2 = 0; k2 < 4; k2++) {
      int off = (k2 * 256 + tid) * 16;
      gload_lds16(src + off, dst + off);
    }
    if (tid < 160) {
      int off = (1024 + tid) * 16;
      gload_lds16(src + off, dst + off);
    }
  }

  const int m = tid & 63;
  const int q = tid >> 6;
  const int n = base + m;

  if (q == 0) {
    const float4* f4 = reinterpret_cast<const float4*>(f + (size_t)n * DIM);
    float v[40];
#pragma unroll
    for (int i = 0; i < 10; i++) {
      float4 t = f4[i];
      v[4 * i] = t.x; v[4 * i + 1] = t.y; v[4 * i + 2] = t.z; v[4 * i + 3] = t.w;
    }
#pragma unroll
    for (int i = 0; i < 16; i++) fsT[i][m] = v[i];
#pragma unroll
    for (int k = 0; k < 24; k++) fvT[(k % 3) * 8 + (k / 3)][m] = v[16 + k];
  } else if (q == 1) {
    const float4* q4 = reinterpret_cast<const float4*>(qd + (size_t)n * DIM);
    float v[40];
#pragma unroll
    for (int i = 0; i < 10; i++) {
      float4 t = q4[i];
      v[4 * i] = t.x; v[4 * i + 1] = t.y; v[4 * i + 2] = t.z; v[4 * i + 3] = t.w;
    }
#pragma unroll
    for (int i = 0; i < 16; i++) qd0T[i][m] = v[i];
#pragma unroll
    for (int k = 0; k < 24; k++) qdvT[(k % 3) * 8 + (k / 3)][m] = v[16 + k];
  }
  __syncthreads();

  const int w    = tid >> 6;
  const int l    = tid & 63;
  const int row  = l & 15;
  const int kb   = l >> 4;
  const int mrow = w * 16 + row;
  const int col  = l & 15;

  f32x4 p0  = {0.f, 0.f, 0.f, 0.f};
  f32x4 pcA = {0.f, 0.f, 0.f, 0.f}, pcB = {0.f, 0.f, 0.f, 0.f}, pcC = {0.f, 0.f, 0.f, 0.f};

#pragma unroll
  for (int s = 0; s < 10; s++) {
    f16x8 a;
    if (s < 8) {
      const int i  = 2 * s + (kb >> 1);
      const int o0 = (kb & 1) * 8;
      const float fsv = fsT[i][mrow];
#pragma unroll
      for (int j = 0; j < 8; j++) a[j] = (_Float16)(fsv * qd0T[o0 + j][mrow]);
    } else {
      const int i = (s - 8) * 4 + kb;
      const float fv0 = fvT[i][mrow], fv1 = fvT[8 + i][mrow], fv2 = fvT[16 + i][mrow];
#pragma unroll
      for (int j = 0; j < 8; j++)
        a[j] = (_Float16)(fv0 * qdvT[j][mrow] + fv1 * qdvT[8 + j][mrow]
                          + fv2 * qdvT[16 + j][mrow]);
    }
    const int k0 = s * 32 + kb * 8;
    f16x8 b = *reinterpret_cast<const f16x8*>(&BL[col * K0P + k0]);
    p0 = __builtin_amdgcn_mfma_f32_16x16x32_f16(a, b, p0, 0, 0, 0);
  }

#pragma unroll
  for (int c = 0; c < 3; c++) {
    f32x4* pc = (c == 0) ? &pcA : (c == 1) ? &pcB : &pcC;
#pragma unroll
    for (int s = 0; s < 8; s++) {
      f16x8 a;
      if (s < 4) {
        const int i  = 2 * s + (kb >> 1);
        const int o0 = (kb & 1) * 8;
        const float fvv = fvT[c * 8 + i][mrow];
#pragma unroll
        for (int j = 0; j < 8; j++) a[j] = (_Float16)(fvv * qd0T[o0 + j][mrow]);
      } else {
        const int i = (s - 4) * 4 + kb;
        const float fsv = fsT[i][mrow];
#pragma unroll
        for (int j = 0; j < 8; j++) a[j] = (_Float16)(fsv * qdvT[c * 8 + j][mrow]);
      }
      const int k0 = s * 32 + kb * 8;
      f16x8 b = *reinterpret_cast<const f16x8*>(&BL[16 * K0P + col * KCP + k0]);
      *pc = __builtin_amdgcn_mfma_f32_16x16x32_f16(a, b, *pc, 0, 0, 0);
    }
  }

  // fp16 output: qq16[node*64 + r*4 + j], r = col
#pragma unroll
  for (int j = 0; j < 4; j++) {
    const int me = w * 16 + kb * 4 + j;
    f16x4 o;
    o[0] = (_Float16)(A_PATH * p0[j]);
    o[1] = (_Float16)(A_PATH * pcA[j]);
    o[2] = (_Float16)(A_PATH * pcB[j]);
    o[3] = (_Float16)(A_PATH * pcC[j]);
    *reinterpret_cast<f16x4*>(qq16 + ((size_t)(base + me) * 16 + col) * 4) = o;
  }
}

// ---------------------------------------------------------------------------
// scan (zeroes z)
// ---------------------------------------------------------------------------
__global__ __launch_bounds__(1024) void scan_kernel(const int* __restrict__ cnt,
                                                    int* __restrict__ off,
                                                    float* __restrict__ z)
{
  __shared__ int part[1024];
  const int t = threadIdx.x;
  const int base = t * 16;
  int loc[16];
  int s = 0;
#pragma unroll
  for (int k = 0; k < 16; k++) { loc[k] = s; s += cnt[base + k]; }
  part[t] = s;
  __syncthreads();
  for (int d = 1; d < 1024; d <<= 1) {
    int v = (t >= d) ? part[t - d] : 0;
    __syncthreads();
    part[t] += v;
    __syncthreads();
  }
  int excl = (t == 0) ? 0 : part[t - 1];
#pragma unroll
  for (int k = 0; k < 16; k++) {
    off[base + k] = excl + loc[k];
    z[base + k] = 0.f;
  }
}

// ---------------------------------------------------------------------------
// edge_kernel (round-15 verified math; qq read fp16, 128B/edge)
// ---------------------------------------------------------------------------
__global__ __launch_bounds__(256) void edge_kernel(
    const int*   __restrict__ ei,
    const float* __restrict__ elen,
    const float* __restrict__ esh,
    const float* __restrict__ emb,
    const float* __restrict__ w1k,    // fck_w1
    const float* __restrict__ w1v,    // fcv_w1
    const _Float16* __restrict__ qq16,
    int*   __restrict__ off,
    float4* __restrict__ edata,       // [NE][4] float4 (64B per edge, by rank)
    float* __restrict__ z)
{
  const int gid = blockIdx.x * 256 + threadIdx.x;

  const int src = ei[gid];
  const int dst = ei[NE + gid];
  const int rk = atomicAdd(&off[dst], 1);

  float el[10];
  const float2* e2 = reinterpret_cast<const float2*>(emb + (size_t)gid * 10);
#pragma unroll
  for (int b = 0; b < 5; b++) { float2 t = e2[b]; el[2 * b] = t.x; el[2 * b + 1] = t.y; }

  // K-side radial h (round-9 verified math)
  float h[16];
#pragma unroll
  for (int j = 0; j < 16; j++) {
    float a = 0.f;
#pragma unroll
    for (int b = 0; b < 10; b++) a += el[b] * w1k[b * 16 + j];
    a *= INV_SQRT_NB;
    float sig = 1.0f / (1.0f + __expf(-a));
    h[j] = a * sig * H_SCALE;
  }

  float4 sh4 = reinterpret_cast<const float4*>(esh)[gid];
  const f16x8* q8 = reinterpret_cast<const f16x8*>(qq16 + (size_t)dst * 64);
  float s = 0.f;
#pragma unroll
  for (int i = 0; i < 8; i++) {
    f16x8 qv = q8[i];
    s += h[2 * i] * (sh4.x * (float)qv[0] + sh4.y * (float)qv[1]
                   + sh4.z * (float)qv[2] + sh4.w * (float)qv[3]);
    s += h[2 * i + 1] * (sh4.x * (float)qv[4] + sh4.y * (float)qv[5]
                       + sh4.z * (float)qv[6] + sh4.w * (float)qv[7]);
  }

  float len = elen[gid];
  float x = 10.0f * (1.0f - len * (1.0f / 1.3f));
  float cut = (x > 0.f) ? __expf(-1.0f / x) : 0.f;
  float ev = cut * __expf(s);
  atomicAdd(&z[dst], ev);

  // V-side radial h (fcv_w1), fp16
  f16x8 hv0, hv1;
#pragma unroll
  for (int j = 0; j < 16; j++) {
    float a = 0.f;
#pragma unroll
    for (int b = 0; b < 10; b++) a += el[b] * w1v[b * 16 + j];
    a *= INV_SQRT_NB;
    float sig = 1.0f / (1.0f + __expf(-a));
    _Float16 hh = (_Float16)(a * sig * H_SCALE);
    if (j < 8) hv0[j] = hh; else hv1[j - 8] = hh;
  }

  float4* ep = edata + (size_t)rk * 4;
  ep[0] = __builtin_bit_cast(float4, hv0);
  ep[1] = __builtin_bit_cast(float4, hv1);
  ep[2] = sh4;
  ep[3] = make_float4(__int_as_float(src), __int_as_float(dst), ev, 0.f);
}

// ---------------------------------------------------------------------------
// V-pass via fp16 MFMA (128 edges/block, two halves; fhalf staging)
// ---------------------------------------------------------------------------
__global__ __launch_bounds__(512) void v_mfma_kernel(
    const _Float16* __restrict__ fhalf,
    const float4* __restrict__ edata,   // by rank, 4 float4 per edge
    const float* __restrict__ z,
    const unsigned short* __restrict__ Bt,
    float* __restrict__ fout)
{
  __shared__ __attribute__((aligned(16))) unsigned short BtL[32][BKP];
  __shared__ __attribute__((aligned(16))) _Float16 h_s[2][64][18];
  __shared__ __attribute__((aligned(16))) _Float16 feE[2][64][FEP];
  __shared__ float scal[2][64][5];
  __shared__ int   nid[2][64];
  __shared__ float rows[2][64][41];
  __shared__ int seg_start[2][64], seg_len[2][64], seg_nid[2][64];
  __shared__ int nseg_s[2];

  const int tid = threadIdx.x;

  {
    const char* src = (const char*)Bt;
    char* dst = (char*)&BtL[0][0];
#pragma unroll
    for (int k = 0; k < 3; k++) {
      int off = (k * 512 + tid) * 16;
      gload_lds16(src + off, dst + off);
    }
    if (tid < 32) {
      int off = (1536 + tid) * 16;
      gload_lds16(src + off, dst + off);
    }
  }

  const int hf  = tid >> 8;
  const int t2  = tid & 255;
  const int m   = t2 & 63;
  const int q   = t2 >> 6;
  const int base = blockIdx.x * 128 + hf * 64;
  const float4* ed = edata + (size_t)(base + m) * 4;

  if (q == 0) {
    float4 v3 = ed[3];
    float4 sh4 = ed[2];
    int dn = __float_as_int(v3.y);
    float zz = z[dn]; zz = (zz == 0.f) ? 1.f : zz;
    float ev = v3.z;
    float wgt = sqrtf(fmaxf(ev / zz, 0.f));
    scal[hf][m][0] = sh4.x; scal[hf][m][1] = sh4.y;
    scal[hf][m][2] = sh4.z; scal[hf][m][3] = sh4.w;
    scal[hf][m][4] = wgt;
    nid[hf][m] = dn;
  } else if (q == 3) {
    int sn = __float_as_int(ed[3].x);
    const f16x8* fp8 = reinterpret_cast<const f16x8*>(fhalf + (size_t)sn * FHP);
    f16x8* fe = reinterpret_cast<f16x8*>(&feE[hf][m][0]);
#pragma unroll
    for (int i = 0; i < 5; i++) fe[i] = fp8[i];
  } else if (q == 1) {
    f16x8 h0 = __builtin_bit_cast(f16x8, ed[0]);
    f16x8 h1 = __builtin_bit_cast(f16x8, ed[1]);
#pragma unroll
    for (int j = 0; j < 8; j++) {
      h_s[hf][m][j]     = h0[j];
      h_s[hf][m][8 + j] = h1[j];
    }
  }
  __syncthreads();

  const int w    = t2 >> 6;
  const int l    = t2 & 63;
  const int row  = l & 15;
  const int kb   = l >> 4;
  const int mrow = w * 16 + row;
  const int col  = l & 15;

  const int i0 = (kb & 1) * 8;
  f16x8 afs = *reinterpret_cast<const f16x8*>(&feE[hf][mrow][i0]);
  f16x8 afv0 = *reinterpret_cast<const f16x8*>(&feE[hf][mrow][16]);
  f16x8 afv1 = *reinterpret_cast<const f16x8*>(&feE[hf][mrow][24]);
  f16x8 afv2 = *reinterpret_cast<const f16x8*>(&feE[hf][mrow][32]);

  f32x4 pfs0 = {0.f, 0.f, 0.f, 0.f}, pfs1 = {0.f, 0.f, 0.f, 0.f};
  f32x4 pc0_0 = {0.f, 0.f, 0.f, 0.f}, pc0_1 = {0.f, 0.f, 0.f, 0.f}, pc0_2 = {0.f, 0.f, 0.f, 0.f};
  f32x4 pc1_0 = {0.f, 0.f, 0.f, 0.f}, pc1_1 = {0.f, 0.f, 0.f, 0.f}, pc1_2 = {0.f, 0.f, 0.f, 0.f};

#pragma unroll
  for (int s = 0; s < 8; s++) {
    const int r  = 2 * s + (kb >> 1);
    const _Float16 hr = h_s[hf][mrow][r];
    f16x8 a;
#pragma unroll
    for (int j = 0; j < 8; j++) a[j] = hr * afs[j];
    const int k0 = s * 32 + kb * 8;
    f16x8 b0 = *reinterpret_cast<const f16x8*>(&BtL[col][k0]);
    f16x8 b1 = *reinterpret_cast<const f16x8*>(&BtL[16 + col][k0]);
    pfs0 = __builtin_amdgcn_mfma_f32_16x16x32_f16(a, b0, pfs0, 0, 0, 0);
    pfs1 = __builtin_amdgcn_mfma_f32_16x16x32_f16(a, b1, pfs1, 0, 0, 0);
  }

#pragma unroll
  for (int s = 0; s < 4; s++) {
    const int r = 4 * s + kb;
    const _Float16 hr = h_s[hf][mrow][r];
    const int k0 = 256 + s * 32 + kb * 8;
    f16x8 b0 = *reinterpret_cast<const f16x8*>(&BtL[col][k0]);
    f16x8 b1 = *reinterpret_cast<const f16x8*>(&BtL[16 + col][k0]);
#pragma unroll
    for (int c = 0; c < 3; c++) {
      const f16x8 av = (c == 0) ? afv0 : (c == 1) ? afv1 : afv2;
      f16x8 a;
#pragma unroll
      for (int j = 0; j < 8; j++) a[j] = hr * av[j];
      f32x4* p0 = (c == 0) ? &pc0_0 : (c == 1) ? &pc0_1 : &pc0_2;
      f32x4* p1 = (c == 0) ? &pc1_0 : (c == 1) ? &pc1_1 : &pc1_2;
      *p0 = __builtin_amdgcn_mfma_f32_16x16x32_f16(a, b0, *p0, 0, 0, 0);
      *p1 = __builtin_amdgcn_mfma_f32_16x16x32_f16(a, b1, *p1, 0, 0, 0);
    }
  }

#pragma unroll
  for (int j = 0; j < 4; j++) {
    const int me = w * 16 + kb * 4 + j;
    const float sh0 = scal[hf][me][0], sh1 = scal[hf][me][1];
    const float sh2 = scal[hf][me][2], sh3 = scal[hf][me][3];
    const float wg = scal[hf][me][4];
    float vsc = sh0 * pfs0[j] + sh1 * pc0_0[j] + sh2 * pc0_1[j] + sh3 * pc0_2[j];
    rows[hf][me][col] = wg * vsc;
    if (col < 8) {
      rows[hf][me][16 + col * 3 + 0] = wg * (sh1 * pfs1[j] + sh0 * pc1_0[j]);
      rows[hf][me][16 + col * 3 + 1] = wg * (sh2 * pfs1[j] + sh0 * pc1_1[j]);
      rows[hf][me][16 + col * 3 + 2] = wg * (sh3 * pfs1[j] + sh0 * pc1_2[j]);
    }
  }
  __syncthreads();

  if (t2 < 64) {
    bool head = (m == 0) || (nid[hf][m] != nid[hf][m - 1]);
    unsigned long long mask = __ballot(head);
    if (t2 == 0) nseg_s[hf] = __popcll(mask);
    if (head) {
      int idx = __popcll(mask & ((1ull << m) - 1ull));
      unsigned long long higher = (m == 63) ? 0ull : (mask >> (m + 1));
      int len = higher ? __ffsll((long long)higher) : (64 - m);
      seg_start[hf][idx] = m; seg_len[hf][idx] = len; seg_nid[hf][idx] = nid[hf][m];
    }
  }
  __syncthreads();

  const int nseg = nseg_s[hf];
  const int d = t2 & 63;
  const int g = t2 >> 6;
  if (d < DIM) {
    for (int s = g; s < nseg; s += 4) {
      const int st = seg_start[hf][s], ln = seg_len[hf][s];
      float acc = 0.f;
      for (int k2 = 0; k2 < ln; k2++) acc += rows[hf][st + k2][d];
      float* fo = &fout[(size_t)seg_nid[hf][s] * DIM + d];
      if (s > 0 && s < nseg - 1) *fo = acc;
      else atomicAdd(fo, acc);
    }
  }
}

extern "C" void kernel_launch(void* const* d_in, const int* in_sizes, int n_in,
                              void* d_out, int out_size, void* d_ws, size_t ws_size,
                              hipStream_t stream) {
  const float* f      = (const float*)d_in[0];
  const int*   ei     = (const int*)d_in[1];
  const float* elen   = (const float*)d_in[2];
  const float* esh    = (const float*)d_in[3];
  const float* emb    = (const float*)d_in[4];
  const float* Wq0    = (const float*)d_in[5];
  const float* Wq1    = (const float*)d_in[6];
  const float* fck_w1 = (const float*)d_in[7];
  const float* fck_w2 = (const float*)d_in[8];
  const float* fcv_w1 = (const float*)d_in[9];
  const float* fcv_w2 = (const float*)d_in[10];
  const float* Wd00   = (const float*)d_in[11];
  const float* Wd11   = (const float*)d_in[12];

  float* out = (float*)d_out;

  char* ws = (char*)d_ws;
  float* qd       = (float*)ws;  ws += (size_t)NN * DIM * 4;
  float* z        = (float*)ws;  ws += (size_t)NN * 4;
  int*   cnt      = (int*)ws;    ws += (size_t)NN * 4;
  int*   off      = (int*)ws;    ws += (size_t)NN * 4;
  ws = (char*)(((size_t)ws + 63) & ~(size_t)63);
  float4* edata   = (float4*)ws; ws += (size_t)NE * 64;          // 16.8 MB
  _Float16* qq16  = (_Float16*)ws; ws += (size_t)NN * 64 * 2;    // 2 MB
  _Float16* fhalf = (_Float16*)ws; ws += (size_t)NN * FHP * 2;   // 1.5 MB
  unsigned short* Btv = (unsigned short*)ws;  ws += (size_t)32 * BKP * 2;
  unsigned short* Btk = (unsigned short*)ws;  ws += (size_t)BKTOT * 2;

  prep_kernel<<<PREP_NODE_BLKS + PREP_BV_BLKS + PREP_BK_BLKS, 256, 0, stream>>>(
      f, Wq0, Wq1, Wd00, Wd11, fcv_w2, fck_w2, qd, fhalf, Btv, Btk, cnt);
  qq_hist_kernel<<<HIST_BLKS + NN / 64, 256, 0, stream>>>(
      ei, cnt, out, f, qd, Btk, qq16);
  scan_kernel<<<1, 1024, 0, stream>>>(cnt, off, z);
  edge_kernel<<<NE / 256, 256, 0, stream>>>(ei, elen, esh, emb, fck_w1, fcv_w1,
                                            qq16, off, edata, z);
  v_mfma_kernel<<<NE / 128, 512, 0, stream>>>(fhalf, edata, z, Btv, out);
}